// Round 6
// baseline (2629.030 us; speedup 1.0000x reference)
//
#include <hip/hip_runtime.h>
#include <hip/hip_bf16.h>
#include <math.h>

#define S_LEN 2048
#define D_DIM 2048
#define NHEAD 16
#define HD_DIM 128
#define NROWS 4096   // B*S
#define BSD 8388608  // NROWS*D_DIM elements (16.78 MB as bf16)

typedef __bf16 bf16x8 __attribute__((ext_vector_type(8)));
typedef float f32x4 __attribute__((ext_vector_type(4)));
typedef unsigned short u16;
typedef unsigned int u32;

__device__ __forceinline__ float bf2f(u16 h) {
    union { u32 u; float f; } v; v.u = ((u32)h) << 16; return v.f;
}
__device__ __forceinline__ u16 f2bf(float f) {
    union { float f; u32 u; } v; v.f = f;
    u32 r = v.u + 0x7fffu + ((v.u >> 16) & 1u);
    return (u16)(r >> 16);
}

// Dtype sniff (validated R5: fires f32 on this harness). Kept for safety.
__device__ __forceinline__ bool detect_f32(const void* p) {
    const u16* h = (const u16*)p;
    int sane = 0;
    for (int i = 0; i < 128; i++) {
        const u16 v = h[2 * i];
        const int e = (v >> 7) & 0xFF;
        sane += (int)((e >= 96 && e <= 150) || ((v & 0x7FFF) == 0));
    }
    return sane < 64;
}

__device__ __forceinline__ bf16x8 load8(const void* X, size_t eidx, bool f32) {
    if (!f32) return *(const bf16x8*)((const u16*)X + eidx);
    const float* xf = (const float*)X + eidx;
    const f32x4 a = *(const f32x4*)xf;
    const f32x4 b = *(const f32x4*)(xf + 4);
    bf16x8 r;
    u16* rp = (u16*)&r;
    rp[0] = f2bf(a[0]); rp[1] = f2bf(a[1]); rp[2] = f2bf(a[2]); rp[3] = f2bf(a[3]);
    rp[4] = f2bf(b[0]); rp[5] = f2bf(b[1]); rp[6] = f2bf(b[2]); rp[7] = f2bf(b[3]);
    return r;
}

__device__ __forceinline__ float bload(const void* b, int i, bool f32) {
    return f32 ? ((const float*)b)[i] : bf2f(((const u16*)b)[i]);
}

// ---------- diagnostic fill (fp32 now) ----------
__global__ __launch_bounds__(256) void fill_k(float* __restrict__ out, float v, int n) {
    const int i = blockIdx.x * 256 + threadIdx.x;
    if (i < n) out[i] = v;
}

// ---------- MFMA QKV projection: X[4096,2048] @ W[2048,2048] + b ----------
// out scatter bf16 [B, 16, S, HD]. 64x64 tile, 256 thr, mfma 16x16x32_bf16.
// (Engine validated bit-exact against VALU ground truth, R3==R4.)
__global__ __launch_bounds__(256) void gemm_qkv(const void* __restrict__ X,
                                                const void* __restrict__ W,
                                                const void* __restrict__ bias,
                                                u16* __restrict__ out) {
    __shared__ __align__(16) u16 a_s[64 * 32];  // [row][k]
    __shared__ __align__(16) u16 b_s[64 * 40];  // [n][k], stride 40
    const bool f32x = detect_f32(X);
    const bool f32w = detect_f32(W);
    const bool f32b = detect_f32(bias);
    const int t = threadIdx.x;
    const int wave = t >> 6, lane = t & 63;
    const int quad = lane >> 4, mrow = lane & 15;
    const int rowBase = blockIdx.y * 64;
    const int colBase = blockIdx.x * 64;
    const int srow = t >> 2, soff = (t & 3) << 3;  // A staging
    const int krow = t >> 3, ncol0 = (t & 7) << 3; // B staging

    f32x4 acc0 = {0.f, 0.f, 0.f, 0.f};
    f32x4 acc1 = acc0, acc2 = acc0, acc3 = acc0;

    for (int k0 = 0; k0 < D_DIM; k0 += 32) {
        const bf16x8 av = load8(X, (size_t)(rowBase + srow) * D_DIM + k0 + soff, f32x);
        const bf16x8 wv = load8(W, (size_t)(k0 + krow) * D_DIM + colBase + ncol0, f32w);
        __syncthreads();
        *(bf16x8*)&a_s[srow * 32 + soff] = av;
        const u16* wp = (const u16*)&wv;
        #pragma unroll
        for (int j = 0; j < 8; j++) b_s[(ncol0 + j) * 40 + krow] = wp[j];
        __syncthreads();
        const bf16x8 af  = *(bf16x8*)&a_s[(wave * 16 + mrow) * 32 + (quad << 3)];
        const bf16x8 bf0 = *(bf16x8*)&b_s[(     mrow) * 40 + (quad << 3)];
        const bf16x8 bf1 = *(bf16x8*)&b_s[(16 + mrow) * 40 + (quad << 3)];
        const bf16x8 bf2 = *(bf16x8*)&b_s[(32 + mrow) * 40 + (quad << 3)];
        const bf16x8 bf3 = *(bf16x8*)&b_s[(48 + mrow) * 40 + (quad << 3)];
        acc0 = __builtin_amdgcn_mfma_f32_16x16x32_bf16(af, bf0, acc0, 0, 0, 0);
        acc1 = __builtin_amdgcn_mfma_f32_16x16x32_bf16(af, bf1, acc1, 0, 0, 0);
        acc2 = __builtin_amdgcn_mfma_f32_16x16x32_bf16(af, bf2, acc2, 0, 0, 0);
        acc3 = __builtin_amdgcn_mfma_f32_16x16x32_bf16(af, bf3, acc3, 0, 0, 0);
    }

    const f32x4 accs[4] = {acc0, acc1, acc2, acc3};
    #pragma unroll
    for (int cb = 0; cb < 4; cb++) {
        const int col = colBase + cb * 16 + mrow;
        const float bv = bload(bias, col, f32b);
        const int h = col >> 7, hd = col & (HD_DIM - 1);
        #pragma unroll
        for (int r = 0; r < 4; r++) {
            const int row = rowBase + wave * 16 + quad * 4 + r;
            const int b = row >> 11, s = row & (S_LEN - 1);
            out[(((size_t)(b * NHEAD + h)) * S_LEN + s) * HD_DIM + hd] =
                f2bf(accs[cb][r] + bv);
        }
    }
}

// ---------- MFMA O-projection: attn-out (bf16 [B,16,S,HD]) @ Wo + bo → fp32 ----------
__global__ __launch_bounds__(256) void gemm_o(const u16* __restrict__ A,
                                              const void* __restrict__ W,
                                              const void* __restrict__ bias,
                                              float* __restrict__ out) {
    __shared__ __align__(16) u16 a_s[64 * 32];
    __shared__ __align__(16) u16 b_s[64 * 40];
    const bool f32w = detect_f32(W);
    const bool f32b = detect_f32(bias);
    const int t = threadIdx.x;
    const int wave = t >> 6, lane = t & 63;
    const int quad = lane >> 4, mrow = lane & 15;
    const int rowBase = blockIdx.y * 64;
    const int colBase = blockIdx.x * 64;
    const int srow = t >> 2, soff = (t & 3) << 3;
    const int krow = t >> 3, ncol0 = (t & 7) << 3;

    f32x4 acc0 = {0.f, 0.f, 0.f, 0.f};
    f32x4 acc1 = acc0, acc2 = acc0, acc3 = acc0;

    const int row = rowBase + srow;
    const int rb = row >> 11, rs = row & (S_LEN - 1);

    for (int k0 = 0; k0 < D_DIM; k0 += 32) {
        const int kg = k0 + soff;
        const int h = kg >> 7, hd = kg & (HD_DIM - 1);
        const bf16x8 av = *(const bf16x8*)&A[
            (((size_t)(rb * NHEAD + h)) * S_LEN + rs) * HD_DIM + hd];
        const bf16x8 wv = load8(W, (size_t)(k0 + krow) * D_DIM + colBase + ncol0, f32w);
        __syncthreads();
        *(bf16x8*)&a_s[srow * 32 + soff] = av;
        const u16* wp = (const u16*)&wv;
        #pragma unroll
        for (int j = 0; j < 8; j++) b_s[(ncol0 + j) * 40 + krow] = wp[j];
        __syncthreads();
        const bf16x8 af  = *(bf16x8*)&a_s[(wave * 16 + mrow) * 32 + (quad << 3)];
        const bf16x8 bf0 = *(bf16x8*)&b_s[(     mrow) * 40 + (quad << 3)];
        const bf16x8 bf1 = *(bf16x8*)&b_s[(16 + mrow) * 40 + (quad << 3)];
        const bf16x8 bf2 = *(bf16x8*)&b_s[(32 + mrow) * 40 + (quad << 3)];
        const bf16x8 bf3 = *(bf16x8*)&b_s[(48 + mrow) * 40 + (quad << 3)];
        acc0 = __builtin_amdgcn_mfma_f32_16x16x32_bf16(af, bf0, acc0, 0, 0, 0);
        acc1 = __builtin_amdgcn_mfma_f32_16x16x32_bf16(af, bf1, acc1, 0, 0, 0);
        acc2 = __builtin_amdgcn_mfma_f32_16x16x32_bf16(af, bf2, acc2, 0, 0, 0);
        acc3 = __builtin_amdgcn_mfma_f32_16x16x32_bf16(af, bf3, acc3, 0, 0, 0);
    }

    const f32x4 accs[4] = {acc0, acc1, acc2, acc3};
    #pragma unroll
    for (int cb = 0; cb < 4; cb++) {
        const int col = colBase + cb * 16 + mrow;
        const float bv = bload(bias, col, f32b);
        #pragma unroll
        for (int r = 0; r < 4; r++) {
            const int orow = rowBase + wave * 16 + quad * 4 + r;
            out[(size_t)orow * D_DIM + col] = accs[cb][r] + bv;  // fp32 write
        }
    }
}

// ---------- RoPE in-place, [B,16,S,HD]; cos/sin stay fp32 (x.dtype=f32) ----------
__global__ __launch_bounds__(256) void rope_k(u16* __restrict__ q, u16* __restrict__ k) {
    const int idx = blockIdx.x * 256 + threadIdx.x;  // 0 .. 32*2048*64
    u16* p = blockIdx.y ? k : q;
    const int i  = idx & 63;
    const int s  = (idx >> 6) & (S_LEN - 1);
    const int bh = idx >> 17;                        // 0..31
    const size_t base = ((size_t)bh * S_LEN + s) * HD_DIM;
    const float inv = powf(10000.f, -(float)i * (1.f / 64.f));
    const float ang = (float)s * inv;
    const float c = cosf(ang), sn = sinf(ang);
    const float x1 = bf2f(p[base + i]);
    const float x2 = bf2f(p[base + 64 + i]);
    p[base + i]      = f2bf(x1 * c - x2 * sn);
    p[base + 64 + i] = f2bf(x2 * c + x1 * sn);
}

// ---------- causal flash attention, 16 heads ----------
// grid (S/16, 16, 2). Out aliases Q (block overwrites only its own Q rows,
// staged to LDS first). Validated bit-exact vs brute force (R3==R5).
__global__ __launch_bounds__(256) void flash_attn(const u16* Q,
                                                  const u16* __restrict__ K,
                                                  const u16* __restrict__ V,
                                                  u16* Out) {
    __shared__ __align__(16) u16 q_s[16 * 128];
    __shared__ __align__(16) u16 k_s[16 * 132];
    __shared__ __align__(16) u16 v_s[16 * 128];
    __shared__ float p_s[16 * 17];
    const int t = threadIdx.x;
    const int r = t >> 4, c = t & 15;
    const int h = blockIdx.y, b = blockIdx.z;
    const int q0 = blockIdx.x << 4;
    const size_t bhoff = ((size_t)(b * NHEAD + h)) * S_LEN * HD_DIM;
    const int lrow = t >> 4, loff = (t & 15) << 3;

    *(uint4*)&q_s[lrow * 128 + loff] =
        *(const uint4*)&Q[bhoff + (size_t)(q0 + lrow) * HD_DIM + loff];

    float m_i = -1e30f, l_i = 0.f;
    float o[8] = {0, 0, 0, 0, 0, 0, 0, 0};

    for (int kb = 0; kb <= q0; kb += 16) {
        __syncthreads();
        const uint4 kv = *(const uint4*)&K[bhoff + (size_t)(kb + lrow) * HD_DIM + loff];
        *(uint2*)&k_s[lrow * 132 + loff]     = make_uint2(kv.x, kv.y);
        *(uint2*)&k_s[lrow * 132 + loff + 4] = make_uint2(kv.z, kv.w);
        *(uint4*)&v_s[lrow * 128 + loff] =
            *(const uint4*)&V[bhoff + (size_t)(kb + lrow) * HD_DIM + loff];
        __syncthreads();

        float s = 0.f;
        #pragma unroll 16
        for (int d = 0; d < 128; d += 2) {
            const u32 qw = *(const u32*)&q_s[r * 128 + d];
            const u32 kw = *(const u32*)&k_s[c * 132 + d];
            s += bf2f((u16)qw) * bf2f((u16)kw);
            s += bf2f((u16)(qw >> 16)) * bf2f((u16)(kw >> 16));
        }
        s *= 0.08838834764831843f;  // 1/sqrt(128)
        const int qrow = q0 + r, kcol = kb + c;
        if (kcol > qrow) s = -1e30f;

        float mx = s;
        mx = fmaxf(mx, __shfl_xor(mx, 1));
        mx = fmaxf(mx, __shfl_xor(mx, 2));
        mx = fmaxf(mx, __shfl_xor(mx, 4));
        mx = fmaxf(mx, __shfl_xor(mx, 8));
        const float m_new = fmaxf(m_i, mx);
        const float p = (kcol > qrow) ? 0.f : __expf(s - m_new);
        float rs = p;
        rs += __shfl_xor(rs, 1);
        rs += __shfl_xor(rs, 2);
        rs += __shfl_xor(rs, 4);
        rs += __shfl_xor(rs, 8);
        const float alpha = __expf(m_i - m_new);
        m_i = m_new;
        l_i = l_i * alpha + rs;
        p_s[r * 17 + c] = p;
        __syncthreads();

        #pragma unroll
        for (int j = 0; j < 8; j++) o[j] *= alpha;
        #pragma unroll
        for (int kk = 0; kk < 16; kk++) {
            const float pv = p_s[r * 17 + kk];
            #pragma unroll
            for (int j = 0; j < 8; j += 2) {
                const u32 vw = *(const u32*)&v_s[kk * 128 + c * 8 + j];
                o[j]     += pv * bf2f((u16)vw);
                o[j + 1] += pv * bf2f((u16)(vw >> 16));
            }
        }
    }

    const float invl = 1.f / l_i;
    const size_t ob = bhoff + (size_t)(q0 + r) * HD_DIM + c * 8;
    #pragma unroll
    for (int j = 0; j < 8; j++) Out[ob + j] = f2bf(o[j] * invl);
}

// ---------- launch ----------
// fp32 world (established R5): out = 8388608 floats = 33.55 MB.
// Scratch: Q(bf16)->ws[0:16.78MB] (proven >=16.78MB); K,V(bf16)->d_out bytes
// [0:16.78) and [16.78:33.55) MB. gemm_o reads only ws, writes fp32 d_out.
extern "C" void kernel_launch(void* const* d_in, const int* in_sizes, int n_in,
                              void* d_out, int out_size, void* d_ws, size_t ws_size,
                              hipStream_t stream) {
    float* outf = (float*)d_out;

    bool order_ok = (n_in == 11);
    if (order_ok) {
        const int expect[11] = {8388608, 8388608, 8388608, 4194304, 2048,
                                4194304, 2048, 4194304, 2048, 4194304, 2048};
        for (int i = 0; i < 11; i++) order_ok = order_ok && (in_sizes[i] == expect[i]);
    }
    if (!order_ok) {  // signature: error ~= 52.9
        fill_k<<<dim3((out_size + 255) / 256), dim3(256), 0, stream>>>(outf, 50.f, out_size);
        return;
    }
    if (ws_size < (size_t)BSD * sizeof(u16)) {  // signature: error ~= 27.9
        fill_k<<<dim3((out_size + 255) / 256), dim3(256), 0, stream>>>(outf, 25.f, out_size);
        return;
    }

    const void* queries = d_in[0];
    const void* keys    = d_in[1];
    const void* values  = d_in[2];
    const void* Wq = d_in[3]; const void* bq = d_in[4];
    const void* Wk = d_in[5]; const void* bk = d_in[6];
    const void* Wv = d_in[7]; const void* bv = d_in[8];
    const void* Wo = d_in[9]; const void* bo = d_in[10];

    u16* Qb = (u16*)d_ws;          // [B,16,S,HD] bf16; attn-out in-place
    u16* Kb = (u16*)d_out;         // d_out scratch, first 16.78 MB
    u16* Vb = Kb + BSD;            // d_out scratch, second 16.78 MB

    const dim3 tb(256);
    const dim3 gg(32, 64);               // 2048 cols x 4096 rows
    const dim3 gr(16384, 2);             // rope: 32 bh * 2048 s * 64 i / 256
    const dim3 gf(S_LEN / 16, NHEAD, 2);

    gemm_qkv<<<gg, tb, 0, stream>>>(queries, Wq, bq, Qb);
    gemm_qkv<<<gg, tb, 0, stream>>>(keys,    Wk, bk, Kb);
    gemm_qkv<<<gg, tb, 0, stream>>>(values,  Wv, bv, Vb);

    rope_k<<<gr, tb, 0, stream>>>(Qb, Kb);

    flash_attn<<<gf, tb, 0, stream>>>(Qb, Kb, Vb, Qb);

    gemm_o<<<gg, tb, 0, stream>>>(Qb, Wo, bo, outf);
}

// Round 7
// 1525.369 us; speedup vs baseline: 1.7235x; 1.7235x over previous
//
#include <hip/hip_runtime.h>
#include <hip/hip_bf16.h>
#include <math.h>

#define S_LEN 2048
#define D_DIM 2048
#define NHEAD 16
#define HD_DIM 128
#define NROWS 4096   // B*S
#define BSD 8388608  // NROWS*D_DIM elements (16.78 MB as bf16)

typedef __bf16 bf16x8 __attribute__((ext_vector_type(8)));
typedef float f32x4 __attribute__((ext_vector_type(4)));
typedef unsigned short u16;
typedef unsigned int u32;

__device__ __forceinline__ float bf2f(u16 h) {
    union { u32 u; float f; } v; v.u = ((u32)h) << 16; return v.f;
}
__device__ __forceinline__ u16 f2bf(float f) {
    union { float f; u32 u; } v; v.f = f;
    u32 r = v.u + 0x7fffu + ((v.u >> 16) & 1u);
    return (u16)(r >> 16);
}

// Dtype sniff (validated R5/R6: fires f32 on this harness). Kept for safety.
__device__ __forceinline__ bool detect_f32(const void* p) {
    const u16* h = (const u16*)p;
    int sane = 0;
    for (int i = 0; i < 128; i++) {
        const u16 v = h[2 * i];
        const int e = (v >> 7) & 0xFF;
        sane += (int)((e >= 96 && e <= 150) || ((v & 0x7FFF) == 0));
    }
    return sane < 64;
}

__device__ __forceinline__ bf16x8 load8(const void* X, size_t eidx, bool f32) {
    if (!f32) return *(const bf16x8*)((const u16*)X + eidx);
    const float* xf = (const float*)X + eidx;
    const f32x4 a = *(const f32x4*)xf;
    const f32x4 b = *(const f32x4*)(xf + 4);
    bf16x8 r;
    u16* rp = (u16*)&r;
    rp[0] = f2bf(a[0]); rp[1] = f2bf(a[1]); rp[2] = f2bf(a[2]); rp[3] = f2bf(a[3]);
    rp[4] = f2bf(b[0]); rp[5] = f2bf(b[1]); rp[6] = f2bf(b[2]); rp[7] = f2bf(b[3]);
    return r;
}

__device__ __forceinline__ float bload(const void* b, int i, bool f32) {
    return f32 ? ((const float*)b)[i] : bf2f(((const u16*)b)[i]);
}

// ---------- diagnostic fill ----------
__global__ __launch_bounds__(256) void fill_k(float* __restrict__ out, float v, int n) {
    const int i = blockIdx.x * 256 + threadIdx.x;
    if (i < n) out[i] = v;
}

// ---------- MFMA QKV projection: X[4096,2048] @ W[2048,2048] + b ----------
// out scatter bf16 [B, 16, S, HD]. Validated R6.
__global__ __launch_bounds__(256) void gemm_qkv(const void* __restrict__ X,
                                                const void* __restrict__ W,
                                                const void* __restrict__ bias,
                                                u16* __restrict__ out) {
    __shared__ __align__(16) u16 a_s[64 * 32];  // [row][k]
    __shared__ __align__(16) u16 b_s[64 * 40];  // [n][k], stride 40
    const bool f32x = detect_f32(X);
    const bool f32w = detect_f32(W);
    const bool f32b = detect_f32(bias);
    const int t = threadIdx.x;
    const int wave = t >> 6, lane = t & 63;
    const int quad = lane >> 4, mrow = lane & 15;
    const int rowBase = blockIdx.y * 64;
    const int colBase = blockIdx.x * 64;
    const int srow = t >> 2, soff = (t & 3) << 3;
    const int krow = t >> 3, ncol0 = (t & 7) << 3;

    f32x4 acc0 = {0.f, 0.f, 0.f, 0.f};
    f32x4 acc1 = acc0, acc2 = acc0, acc3 = acc0;

    for (int k0 = 0; k0 < D_DIM; k0 += 32) {
        const bf16x8 av = load8(X, (size_t)(rowBase + srow) * D_DIM + k0 + soff, f32x);
        const bf16x8 wv = load8(W, (size_t)(k0 + krow) * D_DIM + colBase + ncol0, f32w);
        __syncthreads();
        *(bf16x8*)&a_s[srow * 32 + soff] = av;
        const u16* wp = (const u16*)&wv;
        #pragma unroll
        for (int j = 0; j < 8; j++) b_s[(ncol0 + j) * 40 + krow] = wp[j];
        __syncthreads();
        const bf16x8 af  = *(bf16x8*)&a_s[(wave * 16 + mrow) * 32 + (quad << 3)];
        const bf16x8 bf0 = *(bf16x8*)&b_s[(     mrow) * 40 + (quad << 3)];
        const bf16x8 bf1 = *(bf16x8*)&b_s[(16 + mrow) * 40 + (quad << 3)];
        const bf16x8 bf2 = *(bf16x8*)&b_s[(32 + mrow) * 40 + (quad << 3)];
        const bf16x8 bf3 = *(bf16x8*)&b_s[(48 + mrow) * 40 + (quad << 3)];
        acc0 = __builtin_amdgcn_mfma_f32_16x16x32_bf16(af, bf0, acc0, 0, 0, 0);
        acc1 = __builtin_amdgcn_mfma_f32_16x16x32_bf16(af, bf1, acc1, 0, 0, 0);
        acc2 = __builtin_amdgcn_mfma_f32_16x16x32_bf16(af, bf2, acc2, 0, 0, 0);
        acc3 = __builtin_amdgcn_mfma_f32_16x16x32_bf16(af, bf3, acc3, 0, 0, 0);
    }

    const f32x4 accs[4] = {acc0, acc1, acc2, acc3};
    #pragma unroll
    for (int cb = 0; cb < 4; cb++) {
        const int col = colBase + cb * 16 + mrow;
        const float bv = bload(bias, col, f32b);
        const int h = col >> 7, hd = col & (HD_DIM - 1);
        #pragma unroll
        for (int r = 0; r < 4; r++) {
            const int row = rowBase + wave * 16 + quad * 4 + r;
            const int b = row >> 11, s = row & (S_LEN - 1);
            out[(((size_t)(b * NHEAD + h)) * S_LEN + s) * HD_DIM + hd] =
                f2bf(accs[cb][r] + bv);
        }
    }
}

// ---------- MFMA O-projection: attn-out (bf16 [B,16,S,HD]) @ Wo + bo → fp32 ----------
__global__ __launch_bounds__(256) void gemm_o(const u16* __restrict__ A,
                                              const void* __restrict__ W,
                                              const void* __restrict__ bias,
                                              float* __restrict__ out) {
    __shared__ __align__(16) u16 a_s[64 * 32];
    __shared__ __align__(16) u16 b_s[64 * 40];
    const bool f32w = detect_f32(W);
    const bool f32b = detect_f32(bias);
    const int t = threadIdx.x;
    const int wave = t >> 6, lane = t & 63;
    const int quad = lane >> 4, mrow = lane & 15;
    const int rowBase = blockIdx.y * 64;
    const int colBase = blockIdx.x * 64;
    const int srow = t >> 2, soff = (t & 3) << 3;
    const int krow = t >> 3, ncol0 = (t & 7) << 3;

    f32x4 acc0 = {0.f, 0.f, 0.f, 0.f};
    f32x4 acc1 = acc0, acc2 = acc0, acc3 = acc0;

    const int row = rowBase + srow;
    const int rb = row >> 11, rs = row & (S_LEN - 1);

    for (int k0 = 0; k0 < D_DIM; k0 += 32) {
        const int kg = k0 + soff;
        const int h = kg >> 7, hd = kg & (HD_DIM - 1);
        const bf16x8 av = *(const bf16x8*)&A[
            (((size_t)(rb * NHEAD + h)) * S_LEN + rs) * HD_DIM + hd];
        const bf16x8 wv = load8(W, (size_t)(k0 + krow) * D_DIM + colBase + ncol0, f32w);
        __syncthreads();
        *(bf16x8*)&a_s[srow * 32 + soff] = av;
        const u16* wp = (const u16*)&wv;
        #pragma unroll
        for (int j = 0; j < 8; j++) b_s[(ncol0 + j) * 40 + krow] = wp[j];
        __syncthreads();
        const bf16x8 af  = *(bf16x8*)&a_s[(wave * 16 + mrow) * 32 + (quad << 3)];
        const bf16x8 bf0 = *(bf16x8*)&b_s[(     mrow) * 40 + (quad << 3)];
        const bf16x8 bf1 = *(bf16x8*)&b_s[(16 + mrow) * 40 + (quad << 3)];
        const bf16x8 bf2 = *(bf16x8*)&b_s[(32 + mrow) * 40 + (quad << 3)];
        const bf16x8 bf3 = *(bf16x8*)&b_s[(48 + mrow) * 40 + (quad << 3)];
        acc0 = __builtin_amdgcn_mfma_f32_16x16x32_bf16(af, bf0, acc0, 0, 0, 0);
        acc1 = __builtin_amdgcn_mfma_f32_16x16x32_bf16(af, bf1, acc1, 0, 0, 0);
        acc2 = __builtin_amdgcn_mfma_f32_16x16x32_bf16(af, bf2, acc2, 0, 0, 0);
        acc3 = __builtin_amdgcn_mfma_f32_16x16x32_bf16(af, bf3, acc3, 0, 0, 0);
    }

    const f32x4 accs[4] = {acc0, acc1, acc2, acc3};
    #pragma unroll
    for (int cb = 0; cb < 4; cb++) {
        const int col = colBase + cb * 16 + mrow;
        const float bv = bload(bias, col, f32b);
        #pragma unroll
        for (int r = 0; r < 4; r++) {
            const int orow = rowBase + wave * 16 + quad * 4 + r;
            out[(size_t)orow * D_DIM + col] = accs[cb][r] + bv;
        }
    }
}

// ---------- RoPE in-place, [B,16,S,HD]; cos/sin stay fp32 ----------
__global__ __launch_bounds__(256) void rope_k(u16* __restrict__ q, u16* __restrict__ k) {
    const int idx = blockIdx.x * 256 + threadIdx.x;
    u16* p = blockIdx.y ? k : q;
    const int i  = idx & 63;
    const int s  = (idx >> 6) & (S_LEN - 1);
    const int bh = idx >> 17;
    const size_t base = ((size_t)bh * S_LEN + s) * HD_DIM;
    const float inv = powf(10000.f, -(float)i * (1.f / 64.f));
    const float ang = (float)s * inv;
    const float c = cosf(ang), sn = sinf(ang);
    const float x1 = bf2f(p[base + i]);
    const float x2 = bf2f(p[base + 64 + i]);
    p[base + i]      = f2bf(x1 * c - x2 * sn);
    p[base + 64 + i] = f2bf(x2 * c + x1 * sn);
}

// ---------- MFMA causal flash attention ----------
// grid (S/64, 16, 2), block 256 (4 waves). Per block: 64 Q-rows; per wave: 16.
// K-step 32. QK^T: A=Q rows, B=K rows (both k=d contiguous in LDS, stride 136
// to dodge the power-of-2 bank alias). P round-trips LDS (C-layout -> A-frag).
// V staged transposed (v_s[d][kcol]) for the PV B-operand. Out aliases Q.
__global__ __launch_bounds__(256) void flash_mfma(const u16* Q,
                                                  const u16* __restrict__ K,
                                                  const u16* __restrict__ V,
                                                  u16* Out) {
    __shared__ __align__(16) u16 q_s[64 * 136];   // 17408 B
    __shared__ __align__(16) u16 k_s[32 * 136];   //  8704 B
    __shared__ __align__(16) u16 v_s[128 * 40];   // 10240 B  v_s[d][kcol]
    __shared__ __align__(16) u16 p_s[4 * 16 * 40];//  5120 B  per-wave P
    const int t = threadIdx.x;
    const int wave = t >> 6, lane = t & 63;
    const int quad = lane >> 4, m16 = lane & 15;
    const int h = blockIdx.y, b = blockIdx.z;
    const int q0 = blockIdx.x << 6;
    const size_t bhoff = ((size_t)(b * NHEAD + h)) * S_LEN * HD_DIM;

    // stage Q: 64 rows x 128 (uint4 per thread x4)
    #pragma unroll
    for (int i = 0; i < 4; i++) {
        const int chunk = t + 256 * i;
        const int row = chunk >> 4, d0 = (chunk & 15) << 3;
        *(uint4*)&q_s[row * 136 + d0] =
            *(const uint4*)&Q[bhoff + (size_t)(q0 + row) * HD_DIM + d0];
    }
    __syncthreads();

    // Q A-frags: loop-invariant, keep in registers
    bf16x8 qf[4];
    #pragma unroll
    for (int kc = 0; kc < 4; kc++)
        qf[kc] = *(bf16x8*)&q_s[(wave * 16 + m16) * 136 + kc * 32 + quad * 8];

    f32x4 o[8];
    #pragma unroll
    for (int i = 0; i < 8; i++) o[i] = (f32x4){0.f, 0.f, 0.f, 0.f};
    f32x4 m_i = {-1e30f, -1e30f, -1e30f, -1e30f};
    f32x4 l_i = {0.f, 0.f, 0.f, 0.f};

    const int row_g0 = q0 + wave * 16 + quad * 4;  // + r = this lane's rows
    const float scale = 0.08838834764831843f;       // 1/sqrt(128)

    for (int kb = 0; kb < q0 + 64; kb += 32) {
        __syncthreads();  // protect k_s/v_s from previous iteration's readers
        // stage K (row-major) and V (transposed), 2 chunks/thread
        #pragma unroll
        for (int i = 0; i < 2; i++) {
            const int chunk = t + 256 * i;
            const int row = chunk >> 4, dch = chunk & 15, d0 = dch << 3;
            *(uint4*)&k_s[row * 136 + d0] =
                *(const uint4*)&K[bhoff + (size_t)(kb + row) * HD_DIM + d0];
            const uint4 vv = *(const uint4*)&V[bhoff + (size_t)(kb + row) * HD_DIM + d0];
            const u16* vp = (const u16*)&vv;
            #pragma unroll
            for (int j = 0; j < 8; j++) {
                const int jj = (j + dch) & 7;  // rotate to break bank collision
                v_s[(d0 + jj) * 40 + row] = vp[jj];
            }
        }
        __syncthreads();

        // QK^T: S 16x32 per wave (2 n-tiles x 4 k-chunks)
        f32x4 s0 = {0.f, 0.f, 0.f, 0.f}, s1 = s0;
        #pragma unroll
        for (int kc = 0; kc < 4; kc++) {
            const bf16x8 kf0 = *(bf16x8*)&k_s[m16 * 136 + kc * 32 + quad * 8];
            const bf16x8 kf1 = *(bf16x8*)&k_s[(16 + m16) * 136 + kc * 32 + quad * 8];
            s0 = __builtin_amdgcn_mfma_f32_16x16x32_bf16(qf[kc], kf0, s0, 0, 0, 0);
            s1 = __builtin_amdgcn_mfma_f32_16x16x32_bf16(qf[kc], kf1, s1, 0, 0, 0);
        }

        // online softmax (4 rows per lane; cols spread over the 16-lane group)
        const int kc0 = kb + m16, kc1 = kb + 16 + m16;
        f32x4 mx;
        #pragma unroll
        for (int r = 0; r < 4; r++) {
            float a = s0[r] * scale, c = s1[r] * scale;
            if (kc0 > row_g0 + r) a = -1e30f;
            if (kc1 > row_g0 + r) c = -1e30f;
            s0[r] = a; s1[r] = c;
            mx[r] = fmaxf(a, c);
        }
        #pragma unroll
        for (int d = 1; d <= 8; d <<= 1)
            #pragma unroll
            for (int r = 0; r < 4; r++) mx[r] = fmaxf(mx[r], __shfl_xor(mx[r], d));

        f32x4 alpha, rs;
        #pragma unroll
        for (int r = 0; r < 4; r++) {
            const float mn = fmaxf(m_i[r], mx[r]);
            alpha[r] = __expf(m_i[r] - mn);
            m_i[r] = mn;
            s0[r] = __expf(s0[r] - mn);
            s1[r] = __expf(s1[r] - mn);
            rs[r] = s0[r] + s1[r];
        }
        #pragma unroll
        for (int d = 1; d <= 8; d <<= 1)
            #pragma unroll
            for (int r = 0; r < 4; r++) rs[r] += __shfl_xor(rs[r], d);
        #pragma unroll
        for (int r = 0; r < 4; r++) l_i[r] = l_i[r] * alpha[r] + rs[r];

        // P -> LDS (wave-private; same-wave RAW handled by lgkmcnt)
        #pragma unroll
        for (int r = 0; r < 4; r++) {
            p_s[(wave * 16 + quad * 4 + r) * 40 + m16]      = f2bf(s0[r]);
            p_s[(wave * 16 + quad * 4 + r) * 40 + 16 + m16] = f2bf(s1[r]);
        }

        // rescale O, then PV
        #pragma unroll
        for (int nt = 0; nt < 8; nt++) o[nt] *= alpha;
        const bf16x8 pa = *(bf16x8*)&p_s[(wave * 16 + m16) * 40 + quad * 8];
        #pragma unroll
        for (int nt = 0; nt < 8; nt++) {
            const bf16x8 vb = *(bf16x8*)&v_s[(nt * 16 + m16) * 40 + quad * 8];
            o[nt] = __builtin_amdgcn_mfma_f32_16x16x32_bf16(pa, vb, o[nt], 0, 0, 0);
        }
    }

    // epilogue: normalize and store (Out aliases Q: own rows only)
    f32x4 inv;
    #pragma unroll
    for (int r = 0; r < 4; r++) inv[r] = 1.f / l_i[r];
    #pragma unroll
    for (int nt = 0; nt < 8; nt++)
        #pragma unroll
        for (int r = 0; r < 4; r++)
            Out[bhoff + (size_t)(row_g0 + r) * HD_DIM + nt * 16 + m16] =
                f2bf(o[nt][r] * inv[r]);
}

// ---------- launch ----------
extern "C" void kernel_launch(void* const* d_in, const int* in_sizes, int n_in,
                              void* d_out, int out_size, void* d_ws, size_t ws_size,
                              hipStream_t stream) {
    float* outf = (float*)d_out;

    bool order_ok = (n_in == 11);
    if (order_ok) {
        const int expect[11] = {8388608, 8388608, 8388608, 4194304, 2048,
                                4194304, 2048, 4194304, 2048, 4194304, 2048};
        for (int i = 0; i < 11; i++) order_ok = order_ok && (in_sizes[i] == expect[i]);
    }
    if (!order_ok) {
        fill_k<<<dim3((out_size + 255) / 256), dim3(256), 0, stream>>>(outf, 50.f, out_size);
        return;
    }
    if (ws_size < (size_t)BSD * sizeof(u16)) {
        fill_k<<<dim3((out_size + 255) / 256), dim3(256), 0, stream>>>(outf, 25.f, out_size);
        return;
    }

    const void* queries = d_in[0];
    const void* keys    = d_in[1];
    const void* values  = d_in[2];
    const void* Wq = d_in[3]; const void* bq = d_in[4];
    const void* Wk = d_in[5]; const void* bk = d_in[6];
    const void* Wv = d_in[7]; const void* bv = d_in[8];
    const void* Wo = d_in[9]; const void* bo = d_in[10];

    u16* Qb = (u16*)d_ws;          // [B,16,S,HD] bf16; attn-out in-place
    u16* Kb = (u16*)d_out;         // d_out scratch, first 16.78 MB
    u16* Vb = Kb + BSD;            // d_out scratch, second 16.78 MB

    const dim3 tb(256);
    const dim3 gg(32, 64);
    const dim3 gr(16384, 2);
    const dim3 gf(S_LEN / 64, NHEAD, 2);

    gemm_qkv<<<gg, tb, 0, stream>>>(queries, Wq, bq, Qb);
    gemm_qkv<<<gg, tb, 0, stream>>>(keys,    Wk, bk, Kb);
    gemm_qkv<<<gg, tb, 0, stream>>>(values,  Wv, bv, Vb);

    rope_k<<<gr, tb, 0, stream>>>(Qb, Kb);

    flash_mfma<<<gf, tb, 0, stream>>>(Qb, Kb, Vb, Qb);

    gemm_o<<<gg, tb, 0, stream>>>(Qb, Wo, bo, outf);
}

// Round 8
// 1160.104 us; speedup vs baseline: 2.2662x; 1.3149x over previous
//
#include <hip/hip_runtime.h>
#include <hip/hip_bf16.h>
#include <math.h>

#define S_LEN 2048
#define D_DIM 2048
#define NHEAD 16
#define HD_DIM 128
#define NROWS 4096   // B*S
#define BSD 8388608  // NROWS*D_DIM elements (16.78 MB as bf16)

typedef __bf16 bf16x8 __attribute__((ext_vector_type(8)));
typedef float f32x4 __attribute__((ext_vector_type(4)));
typedef unsigned short u16;
typedef unsigned int u32;

__device__ __forceinline__ float bf2f(u16 h) {
    union { u32 u; float f; } v; v.u = ((u32)h) << 16; return v.f;
}
__device__ __forceinline__ u16 f2bf(float f) {
    union { float f; u32 u; } v; v.f = f;
    u32 r = v.u + 0x7fffu + ((v.u >> 16) & 1u);
    return (u16)(r >> 16);
}

// Dtype sniff (validated R5/R6: fires f32 on this harness).
__device__ __forceinline__ bool detect_f32(const void* p) {
    const u16* h = (const u16*)p;
    int sane = 0;
    for (int i = 0; i < 128; i++) {
        const u16 v = h[2 * i];
        const int e = (v >> 7) & 0xFF;
        sane += (int)((e >= 96 && e <= 150) || ((v & 0x7FFF) == 0));
    }
    return sane < 64;
}

__device__ __forceinline__ bf16x8 load8(const void* X, size_t eidx, bool f32) {
    if (!f32) return *(const bf16x8*)((const u16*)X + eidx);
    const float* xf = (const float*)X + eidx;
    const f32x4 a = *(const f32x4*)xf;
    const f32x4 b = *(const f32x4*)(xf + 4);
    bf16x8 r;
    u16* rp = (u16*)&r;
    rp[0] = f2bf(a[0]); rp[1] = f2bf(a[1]); rp[2] = f2bf(a[2]); rp[3] = f2bf(a[3]);
    rp[4] = f2bf(b[0]); rp[5] = f2bf(b[1]); rp[6] = f2bf(b[2]); rp[7] = f2bf(b[3]);
    return r;
}

__device__ __forceinline__ float bload(const void* b, int i, bool f32) {
    return f32 ? ((const float*)b)[i] : bf2f(((const u16*)b)[i]);
}

// ---------- diagnostic fill ----------
__global__ __launch_bounds__(256) void fill_k(float* __restrict__ out, float v, int n) {
    const int i = blockIdx.x * 256 + threadIdx.x;
    if (i < n) out[i] = v;
}

// ---------- W transpose: [K,N] (fp32 or bf16) -> bf16 [N,K] ----------
__global__ __launch_bounds__(256) void transpose_w(const void* __restrict__ W,
                                                   u16* __restrict__ out) {
    __shared__ float tile[64][68];
    const bool f32w = detect_f32(W);
    const int t = threadIdx.x;
    const int r = t >> 4, c4 = (t & 15) << 2;
    const int kb = blockIdx.y << 6, nb = blockIdx.x << 6;
    if (f32w) {
        #pragma unroll
        for (int i = 0; i < 4; i++) {
            const f32x4 v = *(const f32x4*)((const float*)W +
                (size_t)(kb + r + 16 * i) * D_DIM + nb + c4);
            tile[r + 16 * i][c4 + 0] = v[0];
            tile[r + 16 * i][c4 + 1] = v[1];
            tile[r + 16 * i][c4 + 2] = v[2];
            tile[r + 16 * i][c4 + 3] = v[3];
        }
    } else {
        #pragma unroll
        for (int i = 0; i < 4; i++)
            #pragma unroll
            for (int j = 0; j < 4; j++)
                tile[r + 16 * i][c4 + j] =
                    bf2f(((const u16*)W)[(size_t)(kb + r + 16 * i) * D_DIM + nb + c4 + j]);
    }
    __syncthreads();
    #pragma unroll
    for (int i = 0; i < 4; i++) {
        const int n = nb + r + 16 * i;
        u16 pk[4];
        #pragma unroll
        for (int j = 0; j < 4; j++) pk[j] = f2bf(tile[c4 + j][r + 16 * i]);
        *(uint2*)&out[(size_t)n * D_DIM + kb + c4] = *(uint2*)pk;
    }
}

// ---------- 128x128-tile GEMM vs pre-transposed bf16 WT [N,K] ----------
// MODE 0: X row-major [4096,2048] (fp32/bf16) -> scatter bf16 [B,16,S,HD]
// MODE 1: X bf16 head-major [B,16,S,HD] -> fp32 row-major out
template<int MODE>
__global__ __launch_bounds__(256) void bt_gemm(const void* __restrict__ X,
                                               const u16* __restrict__ WT,
                                               const void* __restrict__ bias,
                                               void* __restrict__ out) {
    __shared__ __align__(16) u16 a_s[128 * 40];  // [row][k], stride 40: 2-way banks
    __shared__ __align__(16) u16 b_s[128 * 40];  // [n][k]
    const bool f32x = (MODE == 0) ? detect_f32(X) : false;
    const bool f32b = detect_f32(bias);
    const int t = threadIdx.x;
    const int wave = t >> 6, lane = t & 63;
    const int quad = lane >> 4, m16 = lane & 15;
    const int wm = (wave >> 1) << 6, wn = (wave & 1) << 6;
    const int rowBase = blockIdx.y << 7, colBase = blockIdx.x << 7;
    const int arow = t >> 2, aoff = (t & 3) << 3;  // staging: 2 chunks of 8 each for A,B

    f32x4 acc[4][4];
    #pragma unroll
    for (int i = 0; i < 4; i++)
        #pragma unroll
        for (int j = 0; j < 4; j++) acc[i][j] = (f32x4){0.f, 0.f, 0.f, 0.f};

    for (int k0 = 0; k0 < D_DIM; k0 += 32) {
        bf16x8 av0, av1;
        if (MODE == 0) {
            av0 = load8(X, (size_t)(rowBase + arow) * D_DIM + k0 + aoff, f32x);
            av1 = load8(X, (size_t)(rowBase + arow + 64) * D_DIM + k0 + aoff, f32x);
        } else {
            const int kg = k0 + aoff, h = kg >> 7, hd = kg & (HD_DIM - 1);
            const int r0 = rowBase + arow, r1 = r0 + 64;
            av0 = *(const bf16x8*)&((const u16*)X)[
                (((size_t)((r0 >> 11) * NHEAD + h)) * S_LEN + (r0 & (S_LEN - 1))) * HD_DIM + hd];
            av1 = *(const bf16x8*)&((const u16*)X)[
                (((size_t)((r1 >> 11) * NHEAD + h)) * S_LEN + (r1 & (S_LEN - 1))) * HD_DIM + hd];
        }
        const bf16x8 bv0 = *(const bf16x8*)&WT[(size_t)(colBase + arow) * D_DIM + k0 + aoff];
        const bf16x8 bv1 = *(const bf16x8*)&WT[(size_t)(colBase + arow + 64) * D_DIM + k0 + aoff];

        __syncthreads();  // previous iteration's frag reads must finish
        *(bf16x8*)&a_s[arow * 40 + aoff]        = av0;
        *(bf16x8*)&a_s[(arow + 64) * 40 + aoff] = av1;
        *(bf16x8*)&b_s[arow * 40 + aoff]        = bv0;
        *(bf16x8*)&b_s[(arow + 64) * 40 + aoff] = bv1;
        __syncthreads();

        bf16x8 af[4], bf[4];
        #pragma unroll
        for (int mi = 0; mi < 4; mi++)
            af[mi] = *(bf16x8*)&a_s[(wm + mi * 16 + m16) * 40 + quad * 8];
        #pragma unroll
        for (int ni = 0; ni < 4; ni++)
            bf[ni] = *(bf16x8*)&b_s[(wn + ni * 16 + m16) * 40 + quad * 8];
        #pragma unroll
        for (int mi = 0; mi < 4; mi++)
            #pragma unroll
            for (int ni = 0; ni < 4; ni++)
                acc[mi][ni] = __builtin_amdgcn_mfma_f32_16x16x32_bf16(
                    af[mi], bf[ni], acc[mi][ni], 0, 0, 0);
    }

    #pragma unroll
    for (int ni = 0; ni < 4; ni++) {
        const int col = colBase + wn + ni * 16 + m16;
        const float bv = bload(bias, col, f32b);
        const int h = col >> 7, hd = col & (HD_DIM - 1);
        #pragma unroll
        for (int mi = 0; mi < 4; mi++) {
            #pragma unroll
            for (int r = 0; r < 4; r++) {
                const int row = rowBase + wm + mi * 16 + quad * 4 + r;
                const float v = acc[mi][ni][r] + bv;
                if (MODE == 0) {
                    const int b = row >> 11, s = row & (S_LEN - 1);
                    ((u16*)out)[(((size_t)(b * NHEAD + h)) * S_LEN + s) * HD_DIM + hd] = f2bf(v);
                } else {
                    ((float*)out)[(size_t)row * D_DIM + col] = v;
                }
            }
        }
    }
}

// ---------- FALLBACK 64-tile GEMMs (validated R6/R7; used if ws too small) ----------
__global__ __launch_bounds__(256) void gemm_qkv(const void* __restrict__ X,
                                                const void* __restrict__ W,
                                                const void* __restrict__ bias,
                                                u16* __restrict__ out) {
    __shared__ __align__(16) u16 a_s[64 * 32];
    __shared__ __align__(16) u16 b_s[64 * 40];
    const bool f32x = detect_f32(X);
    const bool f32w = detect_f32(W);
    const bool f32b = detect_f32(bias);
    const int t = threadIdx.x;
    const int wave = t >> 6, lane = t & 63;
    const int quad = lane >> 4, mrow = lane & 15;
    const int rowBase = blockIdx.y * 64;
    const int colBase = blockIdx.x * 64;
    const int srow = t >> 2, soff = (t & 3) << 3;
    const int krow = t >> 3, ncol0 = (t & 7) << 3;

    f32x4 acc0 = {0.f, 0.f, 0.f, 0.f};
    f32x4 acc1 = acc0, acc2 = acc0, acc3 = acc0;

    for (int k0 = 0; k0 < D_DIM; k0 += 32) {
        const bf16x8 av = load8(X, (size_t)(rowBase + srow) * D_DIM + k0 + soff, f32x);
        const bf16x8 wv = load8(W, (size_t)(k0 + krow) * D_DIM + colBase + ncol0, f32w);
        __syncthreads();
        *(bf16x8*)&a_s[srow * 32 + soff] = av;
        const u16* wp = (const u16*)&wv;
        #pragma unroll
        for (int j = 0; j < 8; j++) b_s[(ncol0 + j) * 40 + krow] = wp[j];
        __syncthreads();
        const bf16x8 af  = *(bf16x8*)&a_s[(wave * 16 + mrow) * 32 + (quad << 3)];
        const bf16x8 bf0 = *(bf16x8*)&b_s[(     mrow) * 40 + (quad << 3)];
        const bf16x8 bf1 = *(bf16x8*)&b_s[(16 + mrow) * 40 + (quad << 3)];
        const bf16x8 bf2 = *(bf16x8*)&b_s[(32 + mrow) * 40 + (quad << 3)];
        const bf16x8 bf3 = *(bf16x8*)&b_s[(48 + mrow) * 40 + (quad << 3)];
        acc0 = __builtin_amdgcn_mfma_f32_16x16x32_bf16(af, bf0, acc0, 0, 0, 0);
        acc1 = __builtin_amdgcn_mfma_f32_16x16x32_bf16(af, bf1, acc1, 0, 0, 0);
        acc2 = __builtin_amdgcn_mfma_f32_16x16x32_bf16(af, bf2, acc2, 0, 0, 0);
        acc3 = __builtin_amdgcn_mfma_f32_16x16x32_bf16(af, bf3, acc3, 0, 0, 0);
    }

    const f32x4 accs[4] = {acc0, acc1, acc2, acc3};
    #pragma unroll
    for (int cb = 0; cb < 4; cb++) {
        const int col = colBase + cb * 16 + mrow;
        const float bv = bload(bias, col, f32b);
        const int h = col >> 7, hd = col & (HD_DIM - 1);
        #pragma unroll
        for (int r = 0; r < 4; r++) {
            const int row = rowBase + wave * 16 + quad * 4 + r;
            const int b = row >> 11, s = row & (S_LEN - 1);
            out[(((size_t)(b * NHEAD + h)) * S_LEN + s) * HD_DIM + hd] =
                f2bf(accs[cb][r] + bv);
        }
    }
}

__global__ __launch_bounds__(256) void gemm_o(const u16* __restrict__ A,
                                              const void* __restrict__ W,
                                              const void* __restrict__ bias,
                                              float* __restrict__ out) {
    __shared__ __align__(16) u16 a_s[64 * 32];
    __shared__ __align__(16) u16 b_s[64 * 40];
    const bool f32w = detect_f32(W);
    const bool f32b = detect_f32(bias);
    const int t = threadIdx.x;
    const int wave = t >> 6, lane = t & 63;
    const int quad = lane >> 4, mrow = lane & 15;
    const int rowBase = blockIdx.y * 64;
    const int colBase = blockIdx.x * 64;
    const int srow = t >> 2, soff = (t & 3) << 3;
    const int krow = t >> 3, ncol0 = (t & 7) << 3;

    f32x4 acc0 = {0.f, 0.f, 0.f, 0.f};
    f32x4 acc1 = acc0, acc2 = acc0, acc3 = acc0;

    const int row = rowBase + srow;
    const int rb = row >> 11, rs = row & (S_LEN - 1);

    for (int k0 = 0; k0 < D_DIM; k0 += 32) {
        const int kg = k0 + soff;
        const int h = kg >> 7, hd = kg & (HD_DIM - 1);
        const bf16x8 av = *(const bf16x8*)&A[
            (((size_t)(rb * NHEAD + h)) * S_LEN + rs) * HD_DIM + hd];
        const bf16x8 wv = load8(W, (size_t)(k0 + krow) * D_DIM + colBase + ncol0, f32w);
        __syncthreads();
        *(bf16x8*)&a_s[srow * 32 + soff] = av;
        const u16* wp = (const u16*)&wv;
        #pragma unroll
        for (int j = 0; j < 8; j++) b_s[(ncol0 + j) * 40 + krow] = wp[j];
        __syncthreads();
        const bf16x8 af  = *(bf16x8*)&a_s[(wave * 16 + mrow) * 32 + (quad << 3)];
        const bf16x8 bf0 = *(bf16x8*)&b_s[(     mrow) * 40 + (quad << 3)];
        const bf16x8 bf1 = *(bf16x8*)&b_s[(16 + mrow) * 40 + (quad << 3)];
        const bf16x8 bf2 = *(bf16x8*)&b_s[(32 + mrow) * 40 + (quad << 3)];
        const bf16x8 bf3 = *(bf16x8*)&b_s[(48 + mrow) * 40 + (quad << 3)];
        acc0 = __builtin_amdgcn_mfma_f32_16x16x32_bf16(af, bf0, acc0, 0, 0, 0);
        acc1 = __builtin_amdgcn_mfma_f32_16x16x32_bf16(af, bf1, acc1, 0, 0, 0);
        acc2 = __builtin_amdgcn_mfma_f32_16x16x32_bf16(af, bf2, acc2, 0, 0, 0);
        acc3 = __builtin_amdgcn_mfma_f32_16x16x32_bf16(af, bf3, acc3, 0, 0, 0);
    }

    const f32x4 accs[4] = {acc0, acc1, acc2, acc3};
    #pragma unroll
    for (int cb = 0; cb < 4; cb++) {
        const int col = colBase + cb * 16 + mrow;
        const float bv = bload(bias, col, f32b);
        #pragma unroll
        for (int r = 0; r < 4; r++) {
            const int orow = rowBase + wave * 16 + quad * 4 + r;
            out[(size_t)orow * D_DIM + col] = accs[cb][r] + bv;
        }
    }
}

// ---------- RoPE in-place, [B,16,S,HD]; cos/sin fp32 ----------
__global__ __launch_bounds__(256) void rope_k(u16* __restrict__ q, u16* __restrict__ k) {
    const int idx = blockIdx.x * 256 + threadIdx.x;
    u16* p = blockIdx.y ? k : q;
    const int i  = idx & 63;
    const int s  = (idx >> 6) & (S_LEN - 1);
    const int bh = idx >> 17;
    const size_t base = ((size_t)bh * S_LEN + s) * HD_DIM;
    const float inv = powf(10000.f, -(float)i * (1.f / 64.f));
    const float ang = (float)s * inv;
    const float c = cosf(ang), sn = sinf(ang);
    const float x1 = bf2f(p[base + i]);
    const float x2 = bf2f(p[base + 64 + i]);
    p[base + i]      = f2bf(x1 * c - x2 * sn);
    p[base + 64 + i] = f2bf(x2 * c + x1 * sn);
}

// ---------- MFMA causal flash attention (validated R7) ----------
__global__ __launch_bounds__(256) void flash_mfma(const u16* Q,
                                                  const u16* __restrict__ K,
                                                  const u16* __restrict__ V,
                                                  u16* Out) {
    __shared__ __align__(16) u16 q_s[64 * 136];
    __shared__ __align__(16) u16 k_s[32 * 136];
    __shared__ __align__(16) u16 v_s[128 * 40];
    __shared__ __align__(16) u16 p_s[4 * 16 * 40];
    const int t = threadIdx.x;
    const int wave = t >> 6, lane = t & 63;
    const int quad = lane >> 4, m16 = lane & 15;
    const int h = blockIdx.y, b = blockIdx.z;
    const int q0 = blockIdx.x << 6;
    const size_t bhoff = ((size_t)(b * NHEAD + h)) * S_LEN * HD_DIM;

    #pragma unroll
    for (int i = 0; i < 4; i++) {
        const int chunk = t + 256 * i;
        const int row = chunk >> 4, d0 = (chunk & 15) << 3;
        *(uint4*)&q_s[row * 136 + d0] =
            *(const uint4*)&Q[bhoff + (size_t)(q0 + row) * HD_DIM + d0];
    }
    __syncthreads();

    bf16x8 qf[4];
    #pragma unroll
    for (int kc = 0; kc < 4; kc++)
        qf[kc] = *(bf16x8*)&q_s[(wave * 16 + m16) * 136 + kc * 32 + quad * 8];

    f32x4 o[8];
    #pragma unroll
    for (int i = 0; i < 8; i++) o[i] = (f32x4){0.f, 0.f, 0.f, 0.f};
    f32x4 m_i = {-1e30f, -1e30f, -1e30f, -1e30f};
    f32x4 l_i = {0.f, 0.f, 0.f, 0.f};

    const int row_g0 = q0 + wave * 16 + quad * 4;
    const float scale = 0.08838834764831843f;

    for (int kb = 0; kb < q0 + 64; kb += 32) {
        __syncthreads();
        #pragma unroll
        for (int i = 0; i < 2; i++) {
            const int chunk = t + 256 * i;
            const int row = chunk >> 4, dch = chunk & 15, d0 = dch << 3;
            *(uint4*)&k_s[row * 136 + d0] =
                *(const uint4*)&K[bhoff + (size_t)(kb + row) * HD_DIM + d0];
            const uint4 vv = *(const uint4*)&V[bhoff + (size_t)(kb + row) * HD_DIM + d0];
            const u16* vp = (const u16*)&vv;
            #pragma unroll
            for (int j = 0; j < 8; j++) {
                const int jj = (j + dch) & 7;
                v_s[(d0 + jj) * 40 + row] = vp[jj];
            }
        }
        __syncthreads();

        f32x4 s0 = {0.f, 0.f, 0.f, 0.f}, s1 = s0;
        #pragma unroll
        for (int kc = 0; kc < 4; kc++) {
            const bf16x8 kf0 = *(bf16x8*)&k_s[m16 * 136 + kc * 32 + quad * 8];
            const bf16x8 kf1 = *(bf16x8*)&k_s[(16 + m16) * 136 + kc * 32 + quad * 8];
            s0 = __builtin_amdgcn_mfma_f32_16x16x32_bf16(qf[kc], kf0, s0, 0, 0, 0);
            s1 = __builtin_amdgcn_mfma_f32_16x16x32_bf16(qf[kc], kf1, s1, 0, 0, 0);
        }

        const int kc0 = kb + m16, kc1 = kb + 16 + m16;
        f32x4 mx;
        #pragma unroll
        for (int r = 0; r < 4; r++) {
            float a = s0[r] * scale, c = s1[r] * scale;
            if (kc0 > row_g0 + r) a = -1e30f;
            if (kc1 > row_g0 + r) c = -1e30f;
            s0[r] = a; s1[r] = c;
            mx[r] = fmaxf(a, c);
        }
        #pragma unroll
        for (int d = 1; d <= 8; d <<= 1)
            #pragma unroll
            for (int r = 0; r < 4; r++) mx[r] = fmaxf(mx[r], __shfl_xor(mx[r], d));

        f32x4 alpha, rs;
        #pragma unroll
        for (int r = 0; r < 4; r++) {
            const float mn = fmaxf(m_i[r], mx[r]);
            alpha[r] = __expf(m_i[r] - mn);
            m_i[r] = mn;
            s0[r] = __expf(s0[r] - mn);
            s1[r] = __expf(s1[r] - mn);
            rs[r] = s0[r] + s1[r];
        }
        #pragma unroll
        for (int d = 1; d <= 8; d <<= 1)
            #pragma unroll
            for (int r = 0; r < 4; r++) rs[r] += __shfl_xor(rs[r], d);
        #pragma unroll
        for (int r = 0; r < 4; r++) l_i[r] = l_i[r] * alpha[r] + rs[r];

        #pragma unroll
        for (int r = 0; r < 4; r++) {
            p_s[(wave * 16 + quad * 4 + r) * 40 + m16]      = f2bf(s0[r]);
            p_s[(wave * 16 + quad * 4 + r) * 40 + 16 + m16] = f2bf(s1[r]);
        }

        #pragma unroll
        for (int nt = 0; nt < 8; nt++) o[nt] *= alpha;
        const bf16x8 pa = *(bf16x8*)&p_s[(wave * 16 + m16) * 40 + quad * 8];
        #pragma unroll
        for (int nt = 0; nt < 8; nt++) {
            const bf16x8 vb = *(bf16x8*)&v_s[(nt * 16 + m16) * 40 + quad * 8];
            o[nt] = __builtin_amdgcn_mfma_f32_16x16x32_bf16(pa, vb, o[nt], 0, 0, 0);
        }
    }

    f32x4 inv;
    #pragma unroll
    for (int r = 0; r < 4; r++) inv[r] = 1.f / l_i[r];
    #pragma unroll
    for (int nt = 0; nt < 8; nt++)
        #pragma unroll
        for (int r = 0; r < 4; r++)
            Out[bhoff + (size_t)(row_g0 + r) * HD_DIM + nt * 16 + m16] =
                f2bf(o[nt][r] * inv[r]);
}

// ---------- launch ----------
extern "C" void kernel_launch(void* const* d_in, const int* in_sizes, int n_in,
                              void* d_out, int out_size, void* d_ws, size_t ws_size,
                              hipStream_t stream) {
    float* outf = (float*)d_out;

    bool order_ok = (n_in == 11);
    if (order_ok) {
        const int expect[11] = {8388608, 8388608, 8388608, 4194304, 2048,
                                4194304, 2048, 4194304, 2048, 4194304, 2048};
        for (int i = 0; i < 11; i++) order_ok = order_ok && (in_sizes[i] == expect[i]);
    }
    if (!order_ok) {
        fill_k<<<dim3((out_size + 255) / 256), dim3(256), 0, stream>>>(outf, 50.f, out_size);
        return;
    }
    if (ws_size < (size_t)BSD * sizeof(u16)) {
        fill_k<<<dim3((out_size + 255) / 256), dim3(256), 0, stream>>>(outf, 25.f, out_size);
        return;
    }

    const void* queries = d_in[0];
    const void* keys    = d_in[1];
    const void* values  = d_in[2];
    const void* Wq = d_in[3]; const void* bq = d_in[4];
    const void* Wk = d_in[5]; const void* bk = d_in[6];
    const void* Wv = d_in[7]; const void* bv = d_in[8];
    const void* Wo = d_in[9]; const void* bo = d_in[10];

    u16* Qb = (u16*)d_ws;          // [B,16,S,HD] bf16; attn-out in-place
    u16* Kb = (u16*)d_out;         // d_out scratch, first 16.78 MB
    u16* Vb = Kb + BSD;            // d_out scratch, second 16.78 MB

    const dim3 tb(256);
    const dim3 gr(16384, 2);
    const dim3 gf(S_LEN / 64, NHEAD, 2);

    const size_t need_fast = (size_t)BSD * 2 + (size_t)D_DIM * D_DIM * 2;  // Qb + WT slot
    if (ws_size >= need_fast) {
        // FAST PATH: pre-transposed weights, 128x128 bt_gemm.
        u16* WT = Qb + BSD;  // 8.39 MB slot, reused serially (stream-ordered)
        const dim3 gt(32, 32);
        const dim3 gb(16, 32);  // 2048/128 cols, 4096/128 rows

        transpose_w<<<gt, tb, 0, stream>>>(Wq, WT);
        bt_gemm<0><<<gb, tb, 0, stream>>>(queries, WT, bq, Qb);
        transpose_w<<<gt, tb, 0, stream>>>(Wk, WT);
        bt_gemm<0><<<gb, tb, 0, stream>>>(keys, WT, bk, Kb);
        transpose_w<<<gt, tb, 0, stream>>>(Wv, WT);
        bt_gemm<0><<<gb, tb, 0, stream>>>(values, WT, bv, Vb);

        rope_k<<<gr, tb, 0, stream>>>(Qb, Kb);
        flash_mfma<<<gf, tb, 0, stream>>>(Qb, Kb, Vb, Qb);

        transpose_w<<<gt, tb, 0, stream>>>(Wo, WT);
        bt_gemm<1><<<gb, tb, 0, stream>>>(Qb, WT, bo, outf);
    } else {
        // FALLBACK (R7 path)
        const dim3 gg(32, 64);
        gemm_qkv<<<gg, tb, 0, stream>>>(queries, Wq, bq, Qb);
        gemm_qkv<<<gg, tb, 0, stream>>>(keys,    Wk, bk, Kb);
        gemm_qkv<<<gg, tb, 0, stream>>>(values,  Wv, bv, Vb);
        rope_k<<<gr, tb, 0, stream>>>(Qb, Kb);
        flash_mfma<<<gf, tb, 0, stream>>>(Qb, Kb, Vb, Qb);
        gemm_o<<<gg, tb, 0, stream>>>(Qb, Wo, bo, outf);
    }
}